// Round 1
// baseline (104.688 us; speedup 1.0000x reference)
//
#include <hip/hip_runtime.h>
#include <hip/hip_bf16.h>

// Problem constants
#define BATCH 4096
#define FIELD 20000
#define EMBED 64
#define KSTEPS 625          // FIELD / 32 k per MFMA step
#define KC     25           // number of K-chunks (cross-block, reduced via atomics)
#define SPW    25           // K-steps per wave = KSTEPS / KC
#define MTILES 256          // BATCH / 16 rows per wave
#define TOTAL_WAVES (MTILES * KC)   // 6400

typedef __attribute__((ext_vector_type(4))) float  f32x4;
typedef __attribute__((ext_vector_type(8))) short  short8;   // 8 bf16 (4 VGPRs) MFMA frag
typedef __attribute__((ext_vector_type(4))) int    i32x4;
typedef __attribute__((ext_vector_type(4))) unsigned int u32x4;

// d_out is poisoned/accumulated-into -> must zero every call (atomics accumulate).
__global__ __launch_bounds__(256) void zero_out_kernel(float* __restrict__ out) {
    out[blockIdx.x * 256 + threadIdx.x] = 0.0f;
}

__device__ __forceinline__ unsigned bf16_rtne(float f) {
    unsigned u = __builtin_bit_cast(unsigned, f);
    return (u + 0x7FFFu + ((u >> 16) & 1u)) >> 16;   // round-to-nearest-even
}

// Pre-swizzle W (f32 [FIELD][EMBED]) into bf16 MFMA-B-fragment order:
// dword index o2 = ((s*4 + t)*64 + lane)*4 + j2  holds  B[k][col], B[k+1][col]
// where k = 32*s + (lane>>4)*8 + 2*j2, col = 16*t + (lane&15).
__global__ __launch_bounds__(256) void prep_w_kernel(const float* __restrict__ W,
                                                     unsigned int* __restrict__ Wswz) {
    int o2 = blockIdx.x * 256 + threadIdx.x;        // 0 .. FIELD*EMBED/2-1 (=640000)
    if (o2 >= FIELD * EMBED / 2) return;
    int j    = (o2 & 3) * 2;
    int lane = (o2 >> 2) & 63;
    int t    = (o2 >> 8) & 3;
    int s    =  o2 >> 10;
    int k    = 32 * s + ((lane >> 4) << 3) + j;
    int col  = 16 * t + (lane & 15);
    float w0 = W[(size_t)k * EMBED + col];
    float w1 = W[(size_t)(k + 1) * EMBED + col];
    Wswz[o2] = bf16_rtne(w0) | (bf16_rtne(w1) << 16);
}

// Main: out = mask(indices) @ W via bf16 MFMA, memory-bound on the indices stream.
// Wave w -> (mtile = w % 256, kc = w / 256). 16 rows x 64 cols per wave,
// SPW K-steps of 32. Partial sums reduced across kc via f32 atomicAdd.
__global__ __launch_bounds__(256) void emb_mfma_kernel(const int* __restrict__ idxm,
                                                       const unsigned int* __restrict__ Wswz,
                                                       float* __restrict__ out) {
    const int lane  = threadIdx.x & 63;
    const int w     = blockIdx.x * 4 + (threadIdx.x >> 6);
    const int mtile = w % MTILES;          // blocks: 4 consecutive mtiles, same kc
    const int kc    = w / MTILES;
    const int lrow  = lane & 15;
    const int khi   = lane >> 4;           // 0..3
    const int row   = mtile * 16 + lrow;

    // A: lane reads indices[row][kbase .. kbase+7] (32 B contiguous, 16B-aligned)
    const i32x4* pA = (const i32x4*)(idxm + (size_t)row * FIELD
                                     + (size_t)kc * SPW * 32 + khi * 8);
    // B: fragment (s,t) at short8 index (s*4+t)*64 + lane
    const short8* pB = (const short8*)Wswz + (size_t)kc * SPW * 4 * 64 + lane;

    f32x4 acc0 = {0.f, 0.f, 0.f, 0.f};
    f32x4 acc1 = acc0, acc2 = acc0, acc3 = acc0;

#pragma unroll 5
    for (int s = 0; s < SPW; ++s) {
        i32x4 x = pA[0];
        i32x4 y = pA[1];
        pA += 8;                            // advance 32 ints (one K-step)

        // mask -> packed bf16 {0, 1.0}: bf16(1.0) == 0x3F80
        unsigned m0 = (x.x != 0 ? 0x3F80u : 0u) | (x.y != 0 ? 0x3F800000u : 0u);
        unsigned m1 = (x.z != 0 ? 0x3F80u : 0u) | (x.w != 0 ? 0x3F800000u : 0u);
        unsigned m2 = (y.x != 0 ? 0x3F80u : 0u) | (y.y != 0 ? 0x3F800000u : 0u);
        unsigned m3 = (y.z != 0 ? 0x3F80u : 0u) | (y.w != 0 ? 0x3F800000u : 0u);
        u32x4 av = {m0, m1, m2, m3};
        short8 afrag = __builtin_bit_cast(short8, av);

        short8 b0 = pB[0];
        short8 b1 = pB[64];
        short8 b2 = pB[128];
        short8 b3 = pB[192];
        pB += 256;

        acc0 = __builtin_amdgcn_mfma_f32_16x16x32_bf16(afrag, b0, acc0, 0, 0, 0);
        acc1 = __builtin_amdgcn_mfma_f32_16x16x32_bf16(afrag, b1, acc1, 0, 0, 0);
        acc2 = __builtin_amdgcn_mfma_f32_16x16x32_bf16(afrag, b2, acc2, 0, 0, 0);
        acc3 = __builtin_amdgcn_mfma_f32_16x16x32_bf16(afrag, b3, acc3, 0, 0, 0);
    }

    // D layout (m89-verified): col = lane&15, row = (lane>>4)*4 + i
    float* obase = out + (size_t)mtile * 16 * EMBED;
#pragma unroll
    for (int i = 0; i < 4; ++i) {
        int orow = khi * 4 + i;
        atomicAdd(obase + (size_t)orow * EMBED +      lrow, acc0[i]);
        atomicAdd(obase + (size_t)orow * EMBED + 16 + lrow, acc1[i]);
        atomicAdd(obase + (size_t)orow * EMBED + 32 + lrow, acc2[i]);
        atomicAdd(obase + (size_t)orow * EMBED + 48 + lrow, acc3[i]);
    }
}

extern "C" void kernel_launch(void* const* d_in, const int* in_sizes, int n_in,
                              void* d_out, int out_size, void* d_ws, size_t ws_size,
                              hipStream_t stream) {
    const int*   idxm = (const int*)d_in[0];     // [4096][20000] int32
    const float* W    = (const float*)d_in[1];   // [20000][64] f32
    float*       out  = (float*)d_out;           // [4096][64] f32
    unsigned int* Wswz = (unsigned int*)d_ws;    // 2.56 MB bf16 swizzled W

    hipLaunchKernelGGL(zero_out_kernel, dim3(BATCH * EMBED / 256), dim3(256), 0, stream, out);
    hipLaunchKernelGGL(prep_w_kernel, dim3(FIELD * EMBED / 2 / 256), dim3(256), 0, stream, W, Wswz);
    hipLaunchKernelGGL(emb_mfma_kernel, dim3(TOTAL_WAVES / 4), dim3(256), 0, stream,
                       idxm, Wswz, out);
}